// Round 2
// baseline (12693.417 us; speedup 1.0000x reference)
//
#include <hip/hip_runtime.h>
#include <math.h>

namespace {
constexpr int   Bb    = 16;
constexpr int   Nn    = 2048;
constexpr int   Mm    = 2048;
constexpr float EPSf  = 0.005f;
constexpr float TOLf  = 1e-3f;
constexpr int   MAXIT = 100;
constexpr float LN2f  = 0.69314718055994531f;
constexpr float C2f   = 288.53900817779268f;   // log2(e)/EPS
constexpr int   BLOCK = 256;
constexpr int   SUBS  = 64;                    // blocks per batch
constexpr int   RPB   = Nn / SUBS;             // rows per block = 32
constexpr int   GRID  = Bb * SUBS;             // 1024
}

__device__ __forceinline__ float ex2(float x) { return __builtin_amdgcn_exp2f(x); }

__device__ __forceinline__ float elem_y(float4 f, float qx, float qy, float qz, float sq1) {
  // reference numerics: d2 = sq1 + sq2 - 2*dot, clamp, sqrt; f.w = pot*C2f
  float sq2 = fmaf(f.z, f.z, fmaf(f.y, f.y, f.x * f.x));
  float dot = fmaf(f.z, qz, fmaf(f.y, qy, f.x * qx));
  float d2  = fmaxf(fmaf(-2.0f, dot, sq1 + sq2), 0.0f);
  float dist = __builtin_amdgcn_sqrtf(d2);
  return fmaf(dist, -C2f, f.w);                // base-2 exponent
}

// natural-log LSE over 2048 staged points; one wave per row, lane-strided.
__device__ __forceinline__ float lse_row(const float4* __restrict__ lds,
                                         float qx, float qy, float qz, float sq1, int lane) {
  float rm = -1e30f, s = 0.0f;
  const float4* p = lds + lane;
  #pragma unroll
  for (int j = 0; j < 32; j += 4) {
    float4 f0 = p[(j + 0) * 64];
    float4 f1 = p[(j + 1) * 64];
    float4 f2 = p[(j + 2) * 64];
    float4 f3 = p[(j + 3) * 64];
    float y0 = elem_y(f0, qx, qy, qz, sq1);
    float y1 = elem_y(f1, qx, qy, qz, sq1);
    float y2 = elem_y(f2, qx, qy, qz, sq1);
    float y3 = elem_y(f3, qx, qy, qz, sq1);
    float pm = fmaxf(fmaxf(y0, y1), fmaxf(y2, y3));
    float nm = fmaxf(rm, pm);
    float sc = ex2(rm - nm);
    float e  = ex2(y0 - nm) + ex2(y1 - nm) + ex2(y2 - nm) + ex2(y3 - nm);
    s = fmaf(s, sc, e);
    rm = nm;
  }
  #pragma unroll
  for (int off = 1; off < 64; off <<= 1) {
    float om = __shfl_xor(rm, off);
    float os = __shfl_xor(s, off);
    float nm = fmaxf(rm, om);
    s = fmaf(s, ex2(rm - nm), os * ex2(om - nm));
    rm = nm;
  }
  return (rm + __builtin_amdgcn_logf(s)) * LN2f;   // v_log_f32 is log2
}

__device__ __forceinline__ void stage(const float* __restrict__ pts,
                                      const float* __restrict__ pot,
                                      float4* lds, int tid) {
  for (int i = tid; i < Mm; i += BLOCK) {
    float x = pts[3 * i + 0];
    float y = pts[3 * i + 1];
    float z = pts[3 * i + 2];
    lds[i] = make_float4(x, y, z, pot[i] * C2f);
  }
}

__global__ __launch_bounds__(BLOCK) void init_ws(unsigned* w, int nwords) {
  int i = blockIdx.x * BLOCK + threadIdx.x;
  if (i < nwords) w[i] = 0u;
}

// One Sinkhorn half-step: update potr (rows of prows) against staged (pcols, potc).
// Freeze semantics: if the previous iteration's max deltas are both < TOL, no-op.
// Frozen iterations never write their slot, so slots stay 0 -> freeze is sticky.
__global__ __launch_bounds__(BLOCK) void sink_pass(
    const float* __restrict__ prows, const float* __restrict__ pcols,
    const float* __restrict__ potc, float* __restrict__ potr,
    unsigned* slot, const unsigned* chku, const unsigned* chkv) {
  if (chku != nullptr) {
    if (__uint_as_float(*chku) < TOLf && __uint_as_float(*chkv) < TOLf) return;
  }
  __shared__ float4 lds[Mm];                    // 32 KB
  const int tid = threadIdx.x, lane = tid & 63, wid = tid >> 6;
  const int b = blockIdx.x >> 6, sub = blockIdx.x & 63;
  const float* PR = prows + b * Nn * 3;
  const float* PC = pcols + b * Mm * 3;
  const float* QC = potc + b * Mm;
  float*       QR = potr + b * Nn;

  stage(PC, QC, lds, tid);
  __syncthreads();

  const float log_ab = logf(1.0f / 2048.0f + 1e-8f);
  float dmax = 0.0f;
  for (int r = wid; r < RPB; r += 4) {
    int n = sub * RPB + r;
    float qx = PR[3 * n], qy = PR[3 * n + 1], qz = PR[3 * n + 2];
    float sq1 = fmaf(qz, qz, fmaf(qy, qy, qx * qx));
    float lse = lse_row(lds, qx, qy, qz, sq1, lane);
    float pnew = EPSf * (log_ab - lse);
    dmax = fmaxf(dmax, fabsf(pnew - QR[n]));
    if (lane == 0) QR[n] = pnew;
  }
  if (lane == 0) atomicMax(slot, __float_as_uint(dmax));
}

// emd_total += sum_{n,m} exp((u+v-dist)/eps) * dist  (per-batch slice per block)
__global__ __launch_bounds__(BLOCK) void final_emd(
    const float* __restrict__ p1, const float* __restrict__ p2,
    const float* __restrict__ U, const float* __restrict__ V, double* etot) {
  __shared__ float4 lds[Mm];
  const int tid = threadIdx.x, lane = tid & 63, wid = tid >> 6;
  const int b = blockIdx.x >> 6, sub = blockIdx.x & 63;
  const float* P1 = p1 + b * Nn * 3;
  const float* P2 = p2 + b * Mm * 3;

  stage(P2, V + b * Mm, lds, tid);
  __syncthreads();

  float acc = 0.0f;
  for (int r = wid; r < RPB; r += 4) {
    int n = sub * RPB + r;
    float qx = P1[3 * n], qy = P1[3 * n + 1], qz = P1[3 * n + 2];
    float sq1 = fmaf(qz, qz, fmaf(qy, qy, qx * qx));
    float uc = U[b * Nn + n] * C2f;
    const float4* p = lds + lane;
    float racc = 0.0f;
    #pragma unroll
    for (int j = 0; j < 32; ++j) {
      float4 f = p[j * 64];
      float sq2 = fmaf(f.z, f.z, fmaf(f.y, f.y, f.x * f.x));
      float dot = fmaf(f.z, qz, fmaf(f.y, qy, f.x * qx));
      float d2  = fmaxf(fmaf(-2.0f, dot, sq1 + sq2), 0.0f);
      float dist = __builtin_amdgcn_sqrtf(d2);
      float y2 = fmaf(dist, -C2f, f.w) + uc;
      racc = fmaf(ex2(y2), dist, racc);
    }
    acc += racc;
  }
  #pragma unroll
  for (int off = 1; off < 64; off <<= 1) acc += __shfl_xor(acc, off);
  if (lane == 0) atomicAdd(etot, (double)acc);
}

__global__ void write_out(const double* etot, float* out) {
  out[0] = (float)(*etot / (double)Bb);
}

extern "C" void kernel_launch(void* const* d_in, const int* in_sizes, int n_in,
                              void* d_out, int out_size, void* d_ws, size_t ws_size,
                              hipStream_t stream) {
  (void)in_sizes; (void)n_in; (void)out_size; (void)ws_size;
  const float* p1 = (const float*)d_in[0];
  const float* p2 = (const float*)d_in[1];
  char* ws = (char*)d_ws;
  float*    U     = (float*)(ws + 0);           // 16*2048 f32
  float*    V     = (float*)(ws + 131072);      // 16*2048 f32
  unsigned* maxdu = (unsigned*)(ws + 262144);   // 100 slots
  unsigned* maxdv = (unsigned*)(ws + 262544);   // 100 slots
  double*   etot  = (double*)(ws + 262944);     // 8-aligned

  const int nwords = 2 * Bb * Nn + 2 * MAXIT + 2;   // U,V + slots + etot
  init_ws<<<(nwords + BLOCK - 1) / BLOCK, BLOCK, 0, stream>>>((unsigned*)ws, nwords);

  for (int it = 0; it < MAXIT; ++it) {
    const unsigned* cu = it ? (maxdu + it - 1) : nullptr;
    const unsigned* cv = it ? (maxdv + it - 1) : nullptr;
    // u-update: rows = p1, staged = (p2, V), writes U
    sink_pass<<<GRID, BLOCK, 0, stream>>>(p1, p2, V, U, maxdu + it, cu, cv);
    // v-update: rows = p2, staged = (p1, U_new), writes V
    sink_pass<<<GRID, BLOCK, 0, stream>>>(p2, p1, U, V, maxdv + it, cu, cv);
  }

  final_emd<<<GRID, BLOCK, 0, stream>>>(p1, p2, U, V, etot);
  write_out<<<1, 1, 0, stream>>>(etot, (float*)d_out);
}

// Round 5
// 11938.525 us; speedup vs baseline: 1.0632x; 1.0632x over previous
//
#include <hip/hip_runtime.h>
#include <math.h>

namespace {
constexpr int   Bb    = 16;
constexpr int   Nn    = 2048;
constexpr int   Mm    = 2048;
constexpr float EPSf  = 0.005f;
constexpr float TOLf  = 1e-3f;
constexpr int   MAXIT = 100;
constexpr float LN2f  = 0.69314718055994531f;
constexpr float C2f   = 288.53900817779268f;   // log2(e)/EPS
constexpr int   BLOCK = 256;
constexpr int   SUBS  = 64;                    // blocks per batch
constexpr int   RPB   = Nn / SUBS;             // rows per block = 32
constexpr int   GRID  = Bb * SUBS;             // 1024
constexpr int   RW    = 8;                     // rows per wave (in registers)
}

__device__ __forceinline__ float ex2(float x) { return __builtin_amdgcn_exp2f(x); }

__device__ __forceinline__ void stage(const float* __restrict__ pts,
                                      const float* __restrict__ pot,
                                      float4* lds, int tid) {
  for (int i = tid; i < Mm; i += BLOCK) {
    float x = pts[3 * i + 0];
    float y = pts[3 * i + 1];
    float z = pts[3 * i + 2];
    lds[i] = make_float4(x, y, z, pot[i] * C2f);
  }
}

__global__ __launch_bounds__(BLOCK) void init_ws(unsigned* w, int nwords) {
  int i = blockIdx.x * BLOCK + threadIdx.x;
  if (i < nwords) w[i] = 0u;
}

// One Sinkhorn half-step. Each wave holds RW=8 query rows in registers and
// scans the staged 2048-point cloud ONCE (8x less LDS traffic than row-serial).
// Freeze semantics: if prev iteration's max deltas both < TOL, no-op; frozen
// iterations never write their slot (stays 0) -> freeze is sticky.
__global__ __launch_bounds__(BLOCK, 4) void sink_pass(
    const float* __restrict__ prows, const float* __restrict__ pcols,
    const float* __restrict__ potc, float* __restrict__ potr,
    unsigned* slot, const unsigned* chku, const unsigned* chkv) {
  if (chku != nullptr) {
    if (__uint_as_float(*chku) < TOLf && __uint_as_float(*chkv) < TOLf) return;
  }
  __shared__ float4 lds[Mm];                    // 32 KB
  const int tid = threadIdx.x, lane = tid & 63, wid = tid >> 6;
  const int b = blockIdx.x >> 6, sub = blockIdx.x & 63;
  const float* PR = prows + b * Nn * 3;
  const float* PC = pcols + b * Mm * 3;

  stage(PC, potc + b * Mm, lds, tid);
  __syncthreads();

  const int base_n = sub * RPB + wid * RW;
  float qx[RW], qy[RW], qz[RW], q1[RW], rm[RW], ss[RW];
  #pragma unroll
  for (int r = 0; r < RW; ++r) {
    int n = base_n + r;
    qx[r] = PR[3 * n]; qy[r] = PR[3 * n + 1]; qz[r] = PR[3 * n + 2];
    q1[r] = fmaf(qz[r], qz[r], fmaf(qy[r], qy[r], qx[r] * qx[r]));
    rm[r] = -1e30f; ss[r] = 0.0f;
  }

  const float4* p = lds + lane;
  for (int j = 0; j < 32; j += 4) {             // 4 points per rescale group
    float4 f0 = p[(j + 0) * 64];
    float4 f1 = p[(j + 1) * 64];
    float4 f2 = p[(j + 2) * 64];
    float4 f3 = p[(j + 3) * 64];
    // |y|^2 shared across all 8 rows
    float s0 = fmaf(f0.z, f0.z, fmaf(f0.y, f0.y, f0.x * f0.x));
    float s1 = fmaf(f1.z, f1.z, fmaf(f1.y, f1.y, f1.x * f1.x));
    float s2 = fmaf(f2.z, f2.z, fmaf(f2.y, f2.y, f2.x * f2.x));
    float s3 = fmaf(f3.z, f3.z, fmaf(f3.y, f3.y, f3.x * f3.x));
    #pragma unroll
    for (int r = 0; r < RW; ++r) {
      float d0 = fmaf(f0.z, qz[r], fmaf(f0.y, qy[r], f0.x * qx[r]));
      float d1 = fmaf(f1.z, qz[r], fmaf(f1.y, qy[r], f1.x * qx[r]));
      float d2 = fmaf(f2.z, qz[r], fmaf(f2.y, qy[r], f2.x * qx[r]));
      float d3 = fmaf(f3.z, qz[r], fmaf(f3.y, qy[r], f3.x * qx[r]));
      float t0 = fmaxf(fmaf(-2.0f, d0, q1[r] + s0), 0.0f);
      float t1 = fmaxf(fmaf(-2.0f, d1, q1[r] + s1), 0.0f);
      float t2 = fmaxf(fmaf(-2.0f, d2, q1[r] + s2), 0.0f);
      float t3 = fmaxf(fmaf(-2.0f, d3, q1[r] + s3), 0.0f);
      float y0 = fmaf(__builtin_amdgcn_sqrtf(t0), -C2f, f0.w);
      float y1 = fmaf(__builtin_amdgcn_sqrtf(t1), -C2f, f1.w);
      float y2 = fmaf(__builtin_amdgcn_sqrtf(t2), -C2f, f2.w);
      float y3 = fmaf(__builtin_amdgcn_sqrtf(t3), -C2f, f3.w);
      float pm = fmaxf(fmaxf(y0, y1), fmaxf(y2, y3));
      float nm = fmaxf(rm[r], pm);
      float e  = ex2(y0 - nm) + ex2(y1 - nm) + ex2(y2 - nm) + ex2(y3 - nm);
      ss[r] = fmaf(ss[r], ex2(rm[r] - nm), e);
      rm[r] = nm;
    }
  }

  const float log_ab = logf(1.0f / 2048.0f + 1e-8f);
  float* QR = potr + b * Nn;
  float dmax = 0.0f;
  #pragma unroll
  for (int r = 0; r < RW; ++r) {
    float rmv = rm[r], sv = ss[r];
    #pragma unroll
    for (int off = 1; off < 64; off <<= 1) {
      float om = __shfl_xor(rmv, off);
      float os = __shfl_xor(sv, off);
      float nm = fmaxf(rmv, om);
      sv = fmaf(sv, ex2(rmv - nm), os * ex2(om - nm));
      rmv = nm;
    }
    float lse = (rmv + __builtin_amdgcn_logf(sv)) * LN2f;  // v_log_f32 is log2
    float pnew = EPSf * (log_ab - lse);
    if (lane == 0) {
      int n = base_n + r;
      dmax = fmaxf(dmax, fabsf(pnew - QR[n]));
      QR[n] = pnew;
    }
  }
  if (lane == 0) atomicMax(slot, __float_as_uint(dmax));
}

// emd_total += sum_{n,m} exp((u+v-dist)/eps) * dist
__global__ __launch_bounds__(BLOCK, 4) void final_emd(
    const float* __restrict__ p1, const float* __restrict__ p2,
    const float* __restrict__ U, const float* __restrict__ V, double* etot) {
  __shared__ float4 lds[Mm];
  const int tid = threadIdx.x, lane = tid & 63, wid = tid >> 6;
  const int b = blockIdx.x >> 6, sub = blockIdx.x & 63;
  const float* P1 = p1 + b * Nn * 3;

  stage(p2 + b * Mm * 3, V + b * Mm, lds, tid);
  __syncthreads();

  const int base_n = sub * RPB + wid * RW;
  float qx[RW], qy[RW], qz[RW], q1[RW], uc[RW], ac[RW];
  #pragma unroll
  for (int r = 0; r < RW; ++r) {
    int n = base_n + r;
    qx[r] = P1[3 * n]; qy[r] = P1[3 * n + 1]; qz[r] = P1[3 * n + 2];
    q1[r] = fmaf(qz[r], qz[r], fmaf(qy[r], qy[r], qx[r] * qx[r]));
    uc[r] = U[b * Nn + n] * C2f;
    ac[r] = 0.0f;
  }

  const float4* p = lds + lane;
  for (int j = 0; j < 32; ++j) {
    float4 f = p[j * 64];
    float sq2 = fmaf(f.z, f.z, fmaf(f.y, f.y, f.x * f.x));
    #pragma unroll
    for (int r = 0; r < RW; ++r) {
      float dot = fmaf(f.z, qz[r], fmaf(f.y, qy[r], f.x * qx[r]));
      float d2  = fmaxf(fmaf(-2.0f, dot, q1[r] + sq2), 0.0f);
      float dist = __builtin_amdgcn_sqrtf(d2);
      float y2 = fmaf(dist, -C2f, f.w) + uc[r];
      ac[r] = fmaf(ex2(y2), dist, ac[r]);
    }
  }
  float acc = 0.0f;
  #pragma unroll
  for (int r = 0; r < RW; ++r) acc += ac[r];
  #pragma unroll
  for (int off = 1; off < 64; off <<= 1) acc += __shfl_xor(acc, off);
  if (lane == 0) atomicAdd(etot, (double)acc);
}

__global__ void write_out(const double* etot, float* out) {
  out[0] = (float)(*etot / (double)Bb);
}

extern "C" void kernel_launch(void* const* d_in, const int* in_sizes, int n_in,
                              void* d_out, int out_size, void* d_ws, size_t ws_size,
                              hipStream_t stream) {
  (void)in_sizes; (void)n_in; (void)out_size; (void)ws_size;
  const float* p1 = (const float*)d_in[0];
  const float* p2 = (const float*)d_in[1];
  char* ws = (char*)d_ws;
  float*    U     = (float*)(ws + 0);           // 16*2048 f32
  float*    V     = (float*)(ws + 131072);      // 16*2048 f32
  unsigned* maxdu = (unsigned*)(ws + 262144);   // 100 slots
  unsigned* maxdv = (unsigned*)(ws + 262544);   // 100 slots
  double*   etot  = (double*)(ws + 262944);     // 8-aligned

  const int nwords = 2 * Bb * Nn + 2 * MAXIT + 2;   // U,V + slots + etot
  init_ws<<<(nwords + BLOCK - 1) / BLOCK, BLOCK, 0, stream>>>((unsigned*)ws, nwords);

  for (int it = 0; it < MAXIT; ++it) {
    const unsigned* cu = it ? (maxdu + it - 1) : nullptr;
    const unsigned* cv = it ? (maxdv + it - 1) : nullptr;
    // u-update: rows = p1, staged = (p2, V), writes U
    sink_pass<<<GRID, BLOCK, 0, stream>>>(p1, p2, V, U, maxdu + it, cu, cv);
    // v-update: rows = p2, staged = (p1, U_new), writes V
    sink_pass<<<GRID, BLOCK, 0, stream>>>(p2, p1, U, V, maxdv + it, cu, cv);
  }

  final_emd<<<GRID, BLOCK, 0, stream>>>(p1, p2, U, V, etot);
  write_out<<<1, 1, 0, stream>>>(etot, (float*)d_out);
}